// Round 5
// baseline (71.420 us; speedup 1.0000x reference)
//
#include <hip/hip_runtime.h>
#include <hip/hip_bf16.h>
#include <cstdint>

// CTC forward loss (keras ctc_batch_cost), B=64 T=1024 L=128 V=512.
// Probability-domain scaled forward algorithm.
//   waves 1-3 (producers): stream FULL 512-float prob rows into an LDS ring
//       with coalesced global_load_lds (width 16). No address divergence.
//   wave 0 (consumer): sequential scan; per-lane label probs gathered from
//       LDS (ds_read_b32), all cross-lane ops are DPP.
// 4-deep LDS ring + counted s_waitcnt vmcnt(N) + raw s_barrier: producers
// stay 3 chunks ahead; HBM latency fully hidden, never drain to 0 mid-loop.
// Renorm every 4 steps by power-of-2 (exact bookkeeping), deferred 1 period.

#define CTC_B 64
#define CTC_T 1024
#define CTC_L 128
#define CTC_V 512
#define BLANK (CTC_V - 1)
#define EPSF 1e-7f
#define LN2F 0.69314718055994530942f

#define CHUNK 16
#define NBUF  4
#define NCH   (CTC_T / CHUNK)   // 64
#define BIASE 60                // renorm scale target = 2^BIASE

__device__ __forceinline__ void gld_lds16(const float* g, float* l) {
    // per-lane global addr g (lane-strided by 16B), LDS dest = uniform base,
    // HW writes base + lane*16
    __builtin_amdgcn_global_load_lds(
        (const __attribute__((address_space(1))) unsigned int*)g,
        (__attribute__((address_space(3))) unsigned int*)l,
        16, 0, 0);
}

template<int CTRL>
__device__ __forceinline__ float dpp_mov0(float v) {
    int r = __builtin_amdgcn_update_dpp(0, __float_as_int(v), CTRL, 0xf, 0xf, false);
    return __int_as_float(r);
}
template<int CTRL>
__device__ __forceinline__ float dpp_max(float v) {
    int r = __builtin_amdgcn_update_dpp(__float_as_int(v), __float_as_int(v),
                                        CTRL, 0xf, 0xf, false);
    return fmaxf(v, __int_as_float(r));
}

__global__ __launch_bounds__(256, 1)
void ctc_fwd_stream(const int* __restrict__ y_true,
                    const float* __restrict__ y_pred,
                    float* __restrict__ out) {
    __shared__ __align__(16) float rows[NBUF][CHUNK][CTC_V];  // 128 KB

    const int b = blockIdx.x;
    const int tid = threadIdx.x;
    const int wave = tid >> 6;
    const int lane = tid & 63;
    const float* __restrict__ yb = y_pred + (size_t)b * CTC_T * CTC_V;

    if (wave != 0) {
        // ----------------- producers: waves 1..3 -----------------
        const int w = wave - 1;  // 0,1,2 ; rows l = w, w+3, ... (6/5/5 rows)
#define ISSUE(c_) do {                                                     \
            const int t0_ = (c_) * CHUNK;                                  \
            float* bufb_ = &rows[(c_) & (NBUF - 1)][0][0];                 \
            for (int l_ = w; l_ < CHUNK; l_ += 3) {                        \
                const float* g_ = yb + (size_t)(t0_ + l_) * CTC_V + lane * 4; \
                float* d_ = bufb_ + l_ * CTC_V;                            \
                gld_lds16(g_, d_);                                         \
                gld_lds16(g_ + 256, d_ + 256);                             \
            }                                                              \
        } while (0)

        ISSUE(0); ISSUE(1); ISSUE(2);      // 3 chunks in flight
        if (w == 0) asm volatile("s_waitcnt vmcnt(24)" ::: "memory");
        else        asm volatile("s_waitcnt vmcnt(20)" ::: "memory");
        __builtin_amdgcn_s_barrier();      // B_0: chunk 0 ready
        __builtin_amdgcn_sched_barrier(0);

        for (int c = 0; c < NCH; ++c) {
            if (c + 3 < NCH) ISSUE(c + 3);
            // drain chunk c+1 (keep 2 newest chunks in flight)
            if (c <= NCH - 4) {
                if (w == 0) asm volatile("s_waitcnt vmcnt(24)" ::: "memory");
                else        asm volatile("s_waitcnt vmcnt(20)" ::: "memory");
            } else if (c == NCH - 3) {
                if (w == 0) asm volatile("s_waitcnt vmcnt(12)" ::: "memory");
                else        asm volatile("s_waitcnt vmcnt(10)" ::: "memory");
            } else if (c == NCH - 2) {
                asm volatile("s_waitcnt vmcnt(0)" ::: "memory");
            }  // c == NCH-1: nothing left
            __builtin_amdgcn_s_barrier();
            __builtin_amdgcn_sched_barrier(0);
        }
        return;
#undef ISSUE
    }

    // ----------------- consumer: wave 0 -----------------
    const int labA = y_true[b * CTC_L + 2 * lane];      // state 4j+1
    const int labB = y_true[b * CTC_L + 2 * lane + 1];  // state 4j+3
    const int labPrev = __shfl_up(labB, 1);
    const float msk1 = (labA != labPrev) ? 1.0f : 0.0f;
    const float msk3 = (labB != labA) ? 1.0f : 0.0f;

    float a0 = 0.0f, a1 = 0.0f, a2 = 0.0f, a3 = 0.0f, a4 = 0.0f;
    float curScale = 1.0f;
    int curE = 0, Eacc = 0;

    // 3 groups of 4 steps prefetched into named registers
    float pAA0, pBA0, blA0, pAA1, pBA1, blA1, pAA2, pBA2, blA2, pAA3, pBA3, blA3;
    float pAB0, pBB0, blB0, pAB1, pBB1, blB1, pAB2, pBB2, blB2, pAB3, pBB3, blB3;
    float pAC0, pBC0, blC0, pAC1, pBC1, blC1, pAC2, pBC2, blC2, pAC3, pBC3, blC3;

#define LOADG(S, l_) do {                                                  \
        const float* r0_ = bufc + ((l_) + 0) * CTC_V;                      \
        const float* r1_ = bufc + ((l_) + 1) * CTC_V;                      \
        const float* r2_ = bufc + ((l_) + 2) * CTC_V;                      \
        const float* r3_ = bufc + ((l_) + 3) * CTC_V;                      \
        pA##S##0 = r0_[labA]; pB##S##0 = r0_[labB]; bl##S##0 = r0_[BLANK]; \
        pA##S##1 = r1_[labA]; pB##S##1 = r1_[labB]; bl##S##1 = r1_[BLANK]; \
        pA##S##2 = r2_[labA]; pB##S##2 = r2_[labB]; bl##S##2 = r2_[BLANK]; \
        pA##S##3 = r3_[labA]; pB##S##3 = r3_[labB]; bl##S##3 = r3_[BLANK]; \
    } while (0)

#define DOSTEP(S, k) do {                                                  \
        const float pb_ = bl##S##k + EPSF;                                 \
        const float pA_ = pA##S##k + EPSF;                                 \
        const float pB_ = pB##S##k + EPSF;                                 \
        const float pm1_ = dpp_mov0<0x138>(a3); /* wave_shr:1, lane0->0 */ \
        const float n0_ = (a0 + pm1_) * pb_;                               \
        const float n1_ = fmaf(msk1, pm1_, a0 + a1) * pA_;                 \
        const float n2_ = (a1 + a2) * pb_;                                 \
        const float n3_ = fmaf(msk3, a1, a2 + a3) * pB_;                   \
        const float n4_ = (a3 + a4) * pb_;                                 \
        a0 = n0_; a1 = n1_; a2 = n2_; a3 = n3_; a4 = n4_;                  \
    } while (0)

#define DORN() do {                                                        \
        a0 *= curScale; a1 *= curScale; a2 *= curScale;                    \
        a3 *= curScale; a4 *= curScale;                                    \
        Eacc += curE;                                                      \
        float m_ = fmaxf(fmaxf(fmaxf(a0, a1), fmaxf(a2, a3)), a4);         \
        m_ = dpp_max<0x111>(m_);  /* row_shr:1  */                         \
        m_ = dpp_max<0x112>(m_);  /* row_shr:2  */                         \
        m_ = dpp_max<0x114>(m_);  /* row_shr:4  */                         \
        m_ = dpp_max<0x118>(m_);  /* row_shr:8  */                         \
        m_ = dpp_max<0x142>(m_);  /* row_bcast:15 */                       \
        m_ = dpp_max<0x143>(m_);  /* row_bcast:31 */                       \
        const int mb_ = __builtin_amdgcn_readlane(__float_as_int(m_), 63); \
        const int e_ = (mb_ >> 23) & 255;                                  \
        int k_ = 127 + BIASE + 127 - e_;                                   \
        k_ = k_ > 254 ? 254 : (k_ < 1 ? 1 : k_);                           \
        curScale = __int_as_float((unsigned)k_ << 23);                     \
        curE = 127 - k_;                                                   \
    } while (0)

#define PROC4_RN(S) do {                                                   \
        DOSTEP(S, 0); DORN();                                              \
        DOSTEP(S, 1); DOSTEP(S, 2); DOSTEP(S, 3);                          \
    } while (0)

    __builtin_amdgcn_s_barrier();   // B_0: chunk 0 ready
    __builtin_amdgcn_sched_barrier(0);

    for (int c = 0; c < NCH; ++c) {
        const float* bufc = &rows[c & (NBUF - 1)][0][0];
        if (c == 0) {
            // t=0 init: states 0 (blank) and 1 (lab[0]) only
            const float pb0 = bufc[BLANK] + EPSF;
            const float plA = bufc[labA] + EPSF;   // lane0's labA = lab[0]
            LOADG(A, 0); LOADG(B, 4); LOADG(C, 8);
            a0 = (lane == 0) ? pb0 : 0.0f;
            a1 = (lane == 0) ? plA : 0.0f;
            DOSTEP(A, 1); DOSTEP(A, 2); DOSTEP(A, 3);   // t = 1..3
            LOADG(A, 12);
            PROC4_RN(B);                                // t = 4..7 (renorm @4)
            PROC4_RN(C);                                // t = 8..11
            PROC4_RN(A);                                // t = 12..15
        } else {
            LOADG(A, 0); LOADG(B, 4); LOADG(C, 8);
            PROC4_RN(A); LOADG(A, 12);
            PROC4_RN(B); PROC4_RN(C); PROC4_RN(A);
        }
        __builtin_amdgcn_s_barrier();
        __builtin_amdgcn_sched_barrier(0);
    }

    // final: -(log(alpha[S-1] + alpha[S-2])), states 255/256 live on lane 63
    if (lane == 63) {
        out[b] = -(logf(a3 + a4) + (float)Eacc * LN2F);
    }

#undef PROC4_RN
#undef DORN
#undef DOSTEP
#undef LOADG
}

extern "C" void kernel_launch(void* const* d_in, const int* in_sizes, int n_in,
                              void* d_out, int out_size, void* d_ws, size_t ws_size,
                              hipStream_t stream) {
    (void)in_sizes; (void)n_in; (void)d_ws; (void)ws_size; (void)out_size;
    const int* y_true = (const int*)d_in[0];     // [B, L] int
    const float* y_pred = (const float*)d_in[1]; // [B, T, V] float32
    float* out = (float*)d_out;                  // [B, 1] float32

    ctc_fwd_stream<<<CTC_B, 256, 0, stream>>>(y_true, y_pred, out);
}